// Round 1
// baseline (3069.057 us; speedup 1.0000x reference)
//
#include <hip/hip_runtime.h>
#include <hip/hip_bf16.h>
#include <math.h>

// Problem constants (see reference: B=4, C=64, H=W=128, RATE=2)
#define B_  4
#define C_  64
#define H_  128
#define W_  128
#define HS  64          // downsampled h
#define WS  64          // downsampled w
#define L_  4096        // HS*WS patches
#define K1  576         // C*3*3  (score GEMM inner dim)
#define E2  1024        // C*4*4  (value dim)

// ---------------- bilinear resize, align_corners=True, 128->64 ----------------
__global__ __launch_bounds__(256) void resize_kernel(const float* __restrict__ fg,
                                                     float* __restrict__ fgs) {
    int idx = blockIdx.x * 256 + threadIdx.x;
    if (idx >= B_ * C_ * HS * WS) return;
    int j = idx & 63, i = (idx >> 6) & 63, bc = idx >> 12;
    const float sc = 127.0f / 63.0f;
    float yf = i * sc, xf = j * sc;
    int y0 = (int)floorf(yf); if (y0 > 127) y0 = 127;
    int x0 = (int)floorf(xf); if (x0 > 127) x0 = 127;
    int y1 = min(y0 + 1, 127), x1 = min(x0 + 1, 127);
    float wy = yf - (float)y0, wx = xf - (float)x0;
    const float* p = fg + (size_t)bc * (H_ * W_);
    float a = p[y0 * W_ + x0], b = p[y0 * W_ + x1];
    float c = p[y1 * W_ + x0], d = p[y1 * W_ + x1];
    float t0 = a * (1.f - wy) + c * wy;
    float t1 = b * (1.f - wy) + d * wy;
    fgs[idx] = t0 * (1.f - wx) + t1 * wx;
}

// ---------------- P[l, k] : 3x3xC patches of fgs (zero pad 1) ----------------
__global__ __launch_bounds__(256) void patch_kernel(const float* __restrict__ fgs_b,
                                                    float* __restrict__ P) {
    int idx = blockIdx.x * 256 + threadIdx.x;
    if (idx >= L_ * K1) return;
    int k = idx % K1, l = idx / K1;
    int c = k / 9, r = k % 9;
    int dy = r / 3, dx = r % 3;
    int ly = l >> 6, lx = l & 63;
    int y = ly - 1 + dy, x = lx - 1 + dx;
    float v = 0.f;
    if ((unsigned)y < 64u && (unsigned)x < 64u) v = fgs_b[c * (HS * WS) + y * WS + x];
    P[idx] = v;
}

// ---------------- patch L2 norms, clamped at EPS_NAN ----------------
__global__ __launch_bounds__(64) void norm_kernel(const float* __restrict__ P,
                                                  float* __restrict__ nrm) {
    int l = blockIdx.x, t = threadIdx.x;
    const float* row = P + (size_t)l * K1;
    float s = 0.f;
    for (int k = t; k < K1; k += 64) { float v = row[k]; s = fmaf(v, v, s); }
    #pragma unroll
    for (int off = 32; off; off >>= 1) s += __shfl_down(s, off);
    if (t == 0) nrm[l] = fmaxf(sqrtf(s), 1e-4f);
}

// ---------------- V[l, e] : 4x4xC background patches (stride 2, pad 1) ----------------
__global__ __launch_bounds__(256) void v_kernel(const float* __restrict__ bg_b,
                                                float* __restrict__ V) {
    int idx = blockIdx.x * 256 + threadIdx.x;
    if (idx >= L_ * E2) return;
    int e = idx & 1023, l = idx >> 10;
    int c = e >> 4, r = e & 15;
    int ky = r >> 2, kx = r & 3;
    int ly = l >> 6, lx = l & 63;
    int by = 2 * ly - 1 + ky, bx = 2 * lx - 1 + kx;
    float v = 0.f;
    if ((unsigned)by < 128u && (unsigned)bx < 128u) v = bg_b[c * (H_ * W_) + by * W_ + bx];
    V[idx] = v;
}

// ---------------- tiled fp32 GEMM: C[M,N] = A[M,K] * op(B), 64x64 tile, BK=16 ----------------
// TRANSB=1: B is [N,K] row-major (use B^T)   -> score GEMM (A=B=P)
// TRANSB=0: B is [K,N] row-major             -> PV GEMM
// colscale: if non-null, multiply column cc by 10/colscale[cc] (score scaling).
template <int TRANSB>
__global__ __launch_bounds__(256) void gemm_kernel(const float* __restrict__ A,
                                                   const float* __restrict__ B,
                                                   float* __restrict__ Cm,
                                                   int K, int lda, int ldb, int ldc,
                                                   const float* __restrict__ colscale) {
    __shared__ __align__(16) float As[16][68];
    __shared__ __align__(16) float Bs[16][68];
    const int tid = threadIdx.x;
    const int tx = tid & 15, ty = tid >> 4;
    const int row0 = blockIdx.y * 64;
    const int col0 = blockIdx.x * 64;
    const int lm  = tid >> 2;          // 0..63
    const int lk4 = (tid & 3) << 2;    // 0,4,8,12
    const int lkk = tid >> 4;          // 0..15
    const int ln4 = (tid & 15) << 2;   // 0..60
    float acc[4][4] = {{0.f}};
    for (int k0 = 0; k0 < K; k0 += 16) {
        float4 av = *(const float4*)(A + (size_t)(row0 + lm) * lda + k0 + lk4);
        As[lk4 + 0][lm] = av.x; As[lk4 + 1][lm] = av.y;
        As[lk4 + 2][lm] = av.z; As[lk4 + 3][lm] = av.w;
        if (TRANSB) {
            float4 bv = *(const float4*)(B + (size_t)(col0 + lm) * ldb + k0 + lk4);
            Bs[lk4 + 0][lm] = bv.x; Bs[lk4 + 1][lm] = bv.y;
            Bs[lk4 + 2][lm] = bv.z; Bs[lk4 + 3][lm] = bv.w;
        } else {
            float4 bv = *(const float4*)(B + (size_t)(k0 + lkk) * ldb + col0 + ln4);
            Bs[lkk][ln4 + 0] = bv.x; Bs[lkk][ln4 + 1] = bv.y;
            Bs[lkk][ln4 + 2] = bv.z; Bs[lkk][ln4 + 3] = bv.w;
        }
        __syncthreads();
        #pragma unroll
        for (int kk = 0; kk < 16; ++kk) {
            float4 a4 = *(const float4*)&As[kk][ty * 4];
            float4 b4 = *(const float4*)&Bs[kk][tx * 4];
            float a[4] = {a4.x, a4.y, a4.z, a4.w};
            float b[4] = {b4.x, b4.y, b4.z, b4.w};
            #pragma unroll
            for (int i2 = 0; i2 < 4; ++i2)
                #pragma unroll
                for (int j2 = 0; j2 < 4; ++j2)
                    acc[i2][j2] = fmaf(a[i2], b[j2], acc[i2][j2]);
        }
        __syncthreads();
    }
    #pragma unroll
    for (int i2 = 0; i2 < 4; ++i2) {
        int r = row0 + ty * 4 + i2;
        #pragma unroll
        for (int j2 = 0; j2 < 4; ++j2) {
            int cc = col0 + tx * 4 + j2;
            float v = acc[i2][j2];
            if (colscale) v *= 10.0f / colscale[cc];
            Cm[(size_t)r * ldc + cc] = v;
        }
    }
}

// ---------------- row-wise softmax over 4096 entries + clip(1e-8) ----------------
__global__ __launch_bounds__(256) void softmax_kernel(float* __restrict__ S) {
    __shared__ float sm[4];
    const int p = blockIdx.x, t = threadIdx.x;
    float* row = S + (size_t)p * L_;
    float m = -1e30f;
    for (int l = t; l < L_; l += 256) m = fmaxf(m, row[l]);
    #pragma unroll
    for (int off = 32; off; off >>= 1) m = fmaxf(m, __shfl_down(m, off));
    if ((t & 63) == 0) sm[t >> 6] = m;
    __syncthreads();
    float M = fmaxf(fmaxf(sm[0], sm[1]), fmaxf(sm[2], sm[3]));
    __syncthreads();
    float s = 0.f;
    for (int l = t; l < L_; l += 256) {
        float e = __expf(row[l] - M);
        row[l] = e;
        s += e;
    }
    #pragma unroll
    for (int off = 32; off; off >>= 1) s += __shfl_down(s, off);
    if ((t & 63) == 0) sm[t >> 6] = s;
    __syncthreads();
    float inv = 1.0f / (sm[0] + sm[1] + sm[2] + sm[3]);
    for (int l = t; l < L_; l += 256) row[l] = fmaxf(row[l] * inv, 1e-8f);
}

// ---------------- conv_transpose overlap-add gather, /4 ----------------
// out[c,Y,X] = 0.25 * sum over ky,kx with Y=2py-1+ky, X=2px-1+kx of OP[p, c*16+ky*4+kx]
__global__ __launch_bounds__(256) void gather_kernel(const float* __restrict__ OP,
                                                     float* __restrict__ out_b) {
    int idx = blockIdx.x * 256 + threadIdx.x;
    if (idx >= C_ * H_ * W_) return;
    int X = idx & 127, Y = (idx >> 7) & 127, c = idx >> 14;
    int kyp = (Y + 1) & 1;
    int kxp = (X + 1) & 1;
    float sum = 0.f;
    #pragma unroll
    for (int ky = kyp; ky < 4; ky += 2) {
        int py = (Y + 1 - ky) >> 1;
        if ((unsigned)py >= 64u) continue;
        #pragma unroll
        for (int kx = kxp; kx < 4; kx += 2) {
            int px = (X + 1 - kx) >> 1;
            if ((unsigned)px >= 64u) continue;
            sum += OP[(size_t)(py * 64 + px) * E2 + c * 16 + ky * 4 + kx];
        }
    }
    out_b[idx] = 0.25f * sum;
}

extern "C" void kernel_launch(void* const* d_in, const int* in_sizes, int n_in,
                              void* d_out, int out_size, void* d_ws, size_t ws_size,
                              hipStream_t stream) {
    const float* bg = (const float*)d_in[0];   // background [4,64,128,128]
    const float* fg = (const float*)d_in[1];   // foreground [4,64,128,128]
    float* out = (float*)d_out;                // [4,64,128,128] fp32
    float* ws  = (float*)d_ws;

    // workspace layout (floats): total ~28.6M floats = ~114 MB
    float* fgs = ws;                              // B*C*HS*WS   = 1,048,576
    float* P   = fgs + (size_t)B_ * C_ * HS * WS; // L*K1        = 2,359,296
    float* nrm = P + (size_t)L_ * K1;             // L           = 4,096
    float* V   = nrm + L_;                        // L*E2        = 4,194,304
    float* S   = V + (size_t)L_ * E2;             // L*L         = 16,777,216
    float* OP  = S + (size_t)L_ * L_;             // L*E2        = 4,194,304

    resize_kernel<<<(B_ * C_ * HS * WS + 255) / 256, 256, 0, stream>>>(fg, fgs);

    for (int b = 0; b < B_; ++b) {
        const float* fgs_b = fgs + (size_t)b * C_ * HS * WS;
        const float* bg_b  = bg + (size_t)b * C_ * H_ * W_;
        float* out_b       = out + (size_t)b * C_ * H_ * W_;

        patch_kernel<<<(L_ * K1 + 255) / 256, 256, 0, stream>>>(fgs_b, P);
        norm_kernel<<<L_, 64, 0, stream>>>(P, nrm);
        v_kernel<<<(L_ * E2 + 255) / 256, 256, 0, stream>>>(bg_b, V);

        // score^T: S[p,l] = 10 * <P[p],P[l]> / nrm[l]
        dim3 g1(L_ / 64, L_ / 64);
        gemm_kernel<1><<<g1, 256, 0, stream>>>(P, P, S, K1, K1, K1, L_, nrm);

        softmax_kernel<<<L_, 256, 0, stream>>>(S);

        // OP[p,e] = sum_l attn[p,l] * V[l,e]
        dim3 g2(E2 / 64, L_ / 64);
        gemm_kernel<0><<<g2, 256, 0, stream>>>(S, V, OP, L_, L_, E2, E2, nullptr);

        gather_kernel<<<(C_ * H_ * W_ + 255) / 256, 256, 0, stream>>>(OP, out_b);
    }
}

// Round 2
// 795.063 us; speedup vs baseline: 3.8601x; 3.8601x over previous
//
#include <hip/hip_runtime.h>
#include <hip/hip_bf16.h>
#include <math.h>

#define B_  4
#define C_  64
#define H_  128
#define W_  128
#define HS  64
#define WS  64
#define L_  4096
#define K1  576
#define E2  1024

typedef _Float16 f16;
typedef f16 f16x8 __attribute__((ext_vector_type(8)));
typedef float f32x4 __attribute__((ext_vector_type(4)));

__device__ __forceinline__ void gload16(const void* g, void* l) {
    __builtin_amdgcn_global_load_lds(
        (const __attribute__((address_space(1))) unsigned int*)g,
        (__attribute__((address_space(3))) unsigned int*)l, 16, 0, 0);
}

// ---------------- bilinear resize 128->64, align_corners ----------------
__global__ __launch_bounds__(256) void resize_kernel(const float* __restrict__ fg,
                                                     float* __restrict__ fgs) {
    int idx = blockIdx.x * 256 + threadIdx.x;
    if (idx >= B_ * C_ * HS * WS) return;
    int j = idx & 63, i = (idx >> 6) & 63, bc = idx >> 12;
    const float sc = 127.0f / 63.0f;
    float yf = i * sc, xf = j * sc;
    int y0 = (int)floorf(yf); if (y0 > 127) y0 = 127;
    int x0 = (int)floorf(xf); if (x0 > 127) x0 = 127;
    int y1 = min(y0 + 1, 127), x1 = min(x0 + 1, 127);
    float wy = yf - (float)y0, wx = xf - (float)x0;
    const float* p = fg + (size_t)bc * (H_ * W_);
    float a = p[y0 * W_ + x0], b = p[y0 * W_ + x1];
    float c = p[y1 * W_ + x0], d = p[y1 * W_ + x1];
    float t0 = a * (1.f - wy) + c * wy;
    float t1 = b * (1.f - wy) + d * wy;
    fgs[idx] = t0 * (1.f - wx) + t1 * wx;
}

// ---------------- P[l,k] f16 patches (3x3xC, zero pad 1), batched ----------------
__global__ __launch_bounds__(256) void patch_kernel(const float* __restrict__ fgs,
                                                    f16* __restrict__ P_all) {
    int idx = blockIdx.x * 256 + threadIdx.x;
    int b = blockIdx.y;
    int k = idx % K1, l = idx / K1;
    int c = k / 9, r = k % 9;
    int dy = r / 3, dx = r % 3;
    int ly = l >> 6, lx = l & 63;
    int y = ly - 1 + dy, x = lx - 1 + dx;
    float v = 0.f;
    if ((unsigned)y < 64u && (unsigned)x < 64u)
        v = fgs[((size_t)b * C_ + c) * (HS * WS) + y * WS + x];
    P_all[(size_t)b * L_ * K1 + idx] = (f16)v;
}

// ---------------- norms of f16 patch rows (fp32 accumulate) ----------------
__global__ __launch_bounds__(64) void norm_kernel(const f16* __restrict__ P_all,
                                                  float* __restrict__ nrm_all) {
    int l = blockIdx.x, b = blockIdx.y, t = threadIdx.x;
    const f16* row = P_all + ((size_t)b * L_ + l) * K1;
    float s = 0.f;
    for (int k = t; k < K1; k += 64) { float v = (float)row[k]; s = fmaf(v, v, s); }
    #pragma unroll
    for (int off = 32; off; off >>= 1) s += __shfl_down(s, off);
    if (t == 0) nrm_all[b * L_ + l] = fmaxf(sqrtf(s), 1e-4f);
}

// ---------------- VT[e,l] f16 : transposed 4x4xC background patches ----------------
__global__ __launch_bounds__(256) void v_kernel(const float* __restrict__ bg,
                                                f16* __restrict__ VT_all) {
    int idx = blockIdx.x * 256 + threadIdx.x;
    int b = blockIdx.y;
    int l = idx & 4095, e = idx >> 12;
    int c = e >> 4, r = e & 15;
    int ky = r >> 2, kx = r & 3;
    int ly = l >> 6, lx = l & 63;
    int by = 2 * ly - 1 + ky, bx = 2 * lx - 1 + kx;
    float v = 0.f;
    if ((unsigned)by < 128u && (unsigned)bx < 128u)
        v = bg[((size_t)b * C_ + c) * (H_ * W_) + by * W_ + bx];
    VT_all[(size_t)b * E2 * L_ + idx] = (f16)v;
}

// ---------------- MFMA gemm_bt: D[M,N] = A[M,K] * Bt[N,K]^T ----------------
// 128x128 tile, 4 waves (2x2 of 64x64), 16x16x32 f16 MFMA, BK=32,
// global_load_lds width-16 staging (m97 structure).
// EPI=1 (score): s = acc*10/nrm[col]; store f16 exp(s - 10*nrm[row]) to Eo.
//   (row max == 10*nrm[row] exactly by Cauchy-Schwarz: diagonal self-match.)
// EPI=0 (PV, split-K over blockIdx.z): atomicAdd fp32 into Co.
template <int EPI>
__global__ __launch_bounds__(256)
void mfma_gemm(const f16* __restrict__ A, const f16* __restrict__ Bt,
               int lda, int ldb, int kLen,
               float* __restrict__ Co, f16* __restrict__ Eo, int ldc,
               const float* __restrict__ nrm) {
    __shared__ __align__(16) f16 As[128 * 32];
    __shared__ __align__(16) f16 Bs[128 * 32];
    const int tid = threadIdx.x;
    const int w = tid >> 6, lane = tid & 63;
    const int row0 = blockIdx.y * 128, col0 = blockIdx.x * 128;
    const int k_start = blockIdx.z * kLen;

    // staging: wave w covers rows [w*32, w*32+32) in two 16-row issues
    const int srow = w * 32 + (lane >> 2);
    const int scol = (lane & 3) * 8;
    const f16* gA = A + (size_t)(row0 + srow) * lda + k_start + scol;
    const f16* gB = Bt + (size_t)(col0 + srow) * ldb + k_start + scol;
    f16* lA0 = As + (w * 32) * 32;
    f16* lA1 = As + (w * 32 + 16) * 32;
    f16* lB0 = Bs + (w * 32) * 32;
    f16* lB1 = Bs + (w * 32 + 16) * 32;

    const int wm = w >> 1, wn = w & 1;
    const int mfm = lane & 15, quad = lane >> 4;
    f32x4 acc[4][4] = {};

    for (int k0 = 0; k0 < kLen; k0 += 32) {
        gload16(gA, lA0);
        gload16(gA + (size_t)16 * lda, lA1);
        gload16(gB, lB0);
        gload16(gB + (size_t)16 * ldb, lB1);
        gA += 32; gB += 32;
        __syncthreads();
        f16x8 af[4], bf[4];
        #pragma unroll
        for (int mi = 0; mi < 4; ++mi)
            af[mi] = *(const f16x8*)&As[(wm * 64 + mi * 16 + mfm) * 32 + quad * 8];
        #pragma unroll
        for (int ni = 0; ni < 4; ++ni)
            bf[ni] = *(const f16x8*)&Bs[(wn * 64 + ni * 16 + mfm) * 32 + quad * 8];
        #pragma unroll
        for (int mi = 0; mi < 4; ++mi)
            #pragma unroll
            for (int ni = 0; ni < 4; ++ni)
                acc[mi][ni] = __builtin_amdgcn_mfma_f32_16x16x32_f16(
                    af[mi], bf[ni], acc[mi][ni], 0, 0, 0);
        __syncthreads();
    }

    const int orow = row0 + wm * 64;
    const int ocol = col0 + wn * 64;
    if (EPI == 1) {
        #pragma unroll
        for (int ni = 0; ni < 4; ++ni) {
            int col = ocol + ni * 16 + mfm;
            float cs = 10.0f / nrm[col];
            #pragma unroll
            for (int mi = 0; mi < 4; ++mi) {
                #pragma unroll
                for (int r = 0; r < 4; ++r) {
                    int row = orow + mi * 16 + quad * 4 + r;
                    float s = acc[mi][ni][r] * cs - 10.0f * nrm[row];
                    Eo[(size_t)row * ldc + col] = (f16)__expf(s);
                }
            }
        }
    } else {
        #pragma unroll
        for (int mi = 0; mi < 4; ++mi) {
            #pragma unroll
            for (int r = 0; r < 4; ++r) {
                int row = orow + mi * 16 + quad * 4 + r;
                #pragma unroll
                for (int ni = 0; ni < 4; ++ni) {
                    int col = ocol + ni * 16 + mfm;
                    atomicAdd(&Co[(size_t)row * ldc + col], acc[mi][ni][r]);
                }
            }
        }
    }
}

// ---------------- row rescale: attn = clip(E / rowsum, 1e-8), in place f16 ----------------
__global__ __launch_bounds__(256) void attn_kernel(f16* __restrict__ E) {
    __shared__ float sm[4];
    int p = blockIdx.x, t = threadIdx.x;
    f16* row = E + (size_t)p * L_;
    f16x8 v0 = *(const f16x8*)&row[t * 16];
    f16x8 v1 = *(const f16x8*)&row[t * 16 + 8];
    float s = 0.f;
    #pragma unroll
    for (int j = 0; j < 8; ++j) { s += (float)v0[j]; s += (float)v1[j]; }
    #pragma unroll
    for (int off = 32; off; off >>= 1) s += __shfl_down(s, off);
    if ((t & 63) == 0) sm[t >> 6] = s;
    __syncthreads();
    float inv = 1.0f / (sm[0] + sm[1] + sm[2] + sm[3]);
    #pragma unroll
    for (int j = 0; j < 8; ++j) {
        v0[j] = (f16)fmaxf((float)v0[j] * inv, 1e-8f);
        v1[j] = (f16)fmaxf((float)v1[j] * inv, 1e-8f);
    }
    *(f16x8*)&row[t * 16] = v0;
    *(f16x8*)&row[t * 16 + 8] = v1;
}

// ---------------- conv_transpose overlap-add gather, /4 ----------------
__global__ __launch_bounds__(256) void gather_kernel(const float* __restrict__ OP,
                                                     float* __restrict__ out_b) {
    int idx = blockIdx.x * 256 + threadIdx.x;
    if (idx >= C_ * H_ * W_) return;
    int X = idx & 127, Y = (idx >> 7) & 127, c = idx >> 14;
    int kyp = (Y + 1) & 1;
    int kxp = (X + 1) & 1;
    float sum = 0.f;
    #pragma unroll
    for (int ky = kyp; ky < 4; ky += 2) {
        int py = (Y + 1 - ky) >> 1;
        if ((unsigned)py >= 64u) continue;
        #pragma unroll
        for (int kx = kxp; kx < 4; kx += 2) {
            int px = (X + 1 - kx) >> 1;
            if ((unsigned)px >= 64u) continue;
            sum += OP[(size_t)(py * 64 + px) * E2 + c * 16 + ky * 4 + kx];
        }
    }
    out_b[idx] = 0.25f * sum;
}

extern "C" void kernel_launch(void* const* d_in, const int* in_sizes, int n_in,
                              void* d_out, int out_size, void* d_ws, size_t ws_size,
                              hipStream_t stream) {
    const float* bg = (const float*)d_in[0];
    const float* fg = (const float*)d_in[1];
    float* out = (float*)d_out;
    char* w8 = (char*)d_ws;

    // workspace layout (bytes), total ~107 MB (round-1 proved >= 114 MB available)
    float* fgs    = (float*)(w8);                       //  4,194,304
    f16*   P_all  = (f16*)  (w8 + 4194304);             // 18,874,368
    float* nrm    = (float*)(w8 + 23068672);            //     65,536
    f16*   VT_all = (f16*)  (w8 + 23134208);            // 33,554,432
    f16*   Eb     = (f16*)  (w8 + 56688640);            // 33,554,432 (per-sample, reused)
    float* OP     = (float*)(w8 + 90243072);            // 16,777,216 (per-sample, reused)

    resize_kernel<<<(B_ * C_ * HS * WS) / 256, 256, 0, stream>>>(fg, fgs);
    patch_kernel<<<dim3((L_ * K1) / 256, B_), 256, 0, stream>>>(fgs, P_all);
    norm_kernel<<<dim3(L_, B_), 64, 0, stream>>>(P_all, nrm);
    v_kernel<<<dim3((L_ * E2) / 256, B_), 256, 0, stream>>>(bg, VT_all);

    for (int b = 0; b < B_; ++b) {
        const f16* P_b  = P_all + (size_t)b * L_ * K1;
        const f16* VT_b = VT_all + (size_t)b * E2 * L_;
        const float* nrm_b = nrm + (size_t)b * L_;
        float* out_b = out + (size_t)b * C_ * H_ * W_;

        // E[p,l] = exp(10*<P_p,P_l>/nrm[l] - 10*nrm[p])  (f16)
        mfma_gemm<1><<<dim3(L_ / 128, L_ / 128, 1), 256, 0, stream>>>(
            P_b, P_b, K1, K1, K1, nullptr, Eb, L_, nrm_b);

        attn_kernel<<<L_, 256, 0, stream>>>(Eb);

        hipMemsetAsync(OP, 0, (size_t)L_ * E2 * sizeof(float), stream);
        // OP[p,e] = sum_l attn[p,l] * VT[e,l]   (split-K=4, atomic accumulate)
        mfma_gemm<0><<<dim3(E2 / 128, L_ / 128, 4), 256, 0, stream>>>(
            Eb, VT_b, L_, L_, L_ / 4, OP, nullptr, E2, nullptr);

        gather_kernel<<<(C_ * H_ * W_) / 256, 256, 0, stream>>>(OP, out_b);
    }
}

// Round 3
// 741.346 us; speedup vs baseline: 4.1398x; 1.0725x over previous
//
#include <hip/hip_runtime.h>
#include <hip/hip_bf16.h>
#include <math.h>

#define B_  4
#define C_  64
#define H_  128
#define W_  128
#define HS  64
#define WS  64
#define L_  4096
#define K1  576
#define E2  1024
#define KSPLIT 4

typedef _Float16 f16;
typedef f16 f16x8 __attribute__((ext_vector_type(8)));
typedef float f32x4 __attribute__((ext_vector_type(4)));

__device__ __forceinline__ void gload16(const void* g, void* l) {
    __builtin_amdgcn_global_load_lds(
        (const __attribute__((address_space(1))) unsigned int*)g,
        (__attribute__((address_space(3))) unsigned int*)l, 16, 0, 0);
}

// ---------------- bilinear resize 128->64, align_corners ----------------
__global__ __launch_bounds__(256) void resize_kernel(const float* __restrict__ fg,
                                                     float* __restrict__ fgs) {
    int idx = blockIdx.x * 256 + threadIdx.x;
    if (idx >= B_ * C_ * HS * WS) return;
    int j = idx & 63, i = (idx >> 6) & 63, bc = idx >> 12;
    const float sc = 127.0f / 63.0f;
    float yf = i * sc, xf = j * sc;
    int y0 = (int)floorf(yf); if (y0 > 127) y0 = 127;
    int x0 = (int)floorf(xf); if (x0 > 127) x0 = 127;
    int y1 = min(y0 + 1, 127), x1 = min(x0 + 1, 127);
    float wy = yf - (float)y0, wx = xf - (float)x0;
    const float* p = fg + (size_t)bc * (H_ * W_);
    float a = p[y0 * W_ + x0], b = p[y0 * W_ + x1];
    float c = p[y1 * W_ + x0], d = p[y1 * W_ + x1];
    float t0 = a * (1.f - wy) + c * wy;
    float t1 = b * (1.f - wy) + d * wy;
    fgs[idx] = t0 * (1.f - wx) + t1 * wx;
}

// ---------------- P[l,k] f16 patches (3x3xC, zero pad 1), batched ----------------
__global__ __launch_bounds__(256) void patch_kernel(const float* __restrict__ fgs,
                                                    f16* __restrict__ P_all) {
    int idx = blockIdx.x * 256 + threadIdx.x;
    int b = blockIdx.y;
    int k = idx % K1, l = idx / K1;
    int c = k / 9, r = k % 9;
    int dy = r / 3, dx = r % 3;
    int ly = l >> 6, lx = l & 63;
    int y = ly - 1 + dy, x = lx - 1 + dx;
    float v = 0.f;
    if ((unsigned)y < 64u && (unsigned)x < 64u)
        v = fgs[((size_t)b * C_ + c) * (HS * WS) + y * WS + x];
    P_all[(size_t)b * L_ * K1 + idx] = (f16)v;
}

// ---------------- norms of f16 patch rows (fp32 accumulate), batched ----------------
__global__ __launch_bounds__(64) void norm_kernel(const f16* __restrict__ P_all,
                                                  float* __restrict__ nrm_all) {
    int l = blockIdx.x, b = blockIdx.y, t = threadIdx.x;
    const f16* row = P_all + ((size_t)b * L_ + l) * K1;
    float s = 0.f;
    for (int k = t; k < K1; k += 64) { float v = (float)row[k]; s = fmaf(v, v, s); }
    #pragma unroll
    for (int off = 32; off; off >>= 1) s += __shfl_down(s, off);
    if (t == 0) nrm_all[b * L_ + l] = fmaxf(sqrtf(s), 1e-4f);
}

// ---------------- VT[e,l] f16 : transposed 4x4xC background patches, per sample ----------------
__global__ __launch_bounds__(256) void v_kernel(const float* __restrict__ bg_b,
                                                f16* __restrict__ VT) {
    int idx = blockIdx.x * 256 + threadIdx.x;
    int l = idx & 4095, e = idx >> 12;
    int c = e >> 4, r = e & 15;
    int ky = r >> 2, kx = r & 3;
    int ly = l >> 6, lx = l & 63;
    int by = 2 * ly - 1 + ky, bx = 2 * lx - 1 + kx;
    float v = 0.f;
    if ((unsigned)by < 128u && (unsigned)bx < 128u)
        v = bg_b[(size_t)c * (H_ * W_) + by * W_ + bx];
    VT[idx] = (f16)v;
}

// ---------------- MFMA gemm_bt: D[M,N] = A[M,K] * Bt[N,K]^T ----------------
// 128x128 tile, 4 waves (2x2 of 64x64), 16x16x32 f16 MFMA, BK=32,
// global_load_lds width-16 staging (m97 structure), XCD-aware block swizzle.
// EPI=1 (score, 32x32 grid): E = exp(acc*10/nrm[col] - 10*nrm[row]) stored f16;
//       per-row wave-reduced E-sums atomicAdd'ed into rowsum[] (softmax denom).
// EPI=0 (PV, 8x32x4 grid, split-K): f16 partials to outp + z*L_*E2 (no atomics).
template <int EPI>
__global__ __launch_bounds__(256)
void mfma_gemm(const f16* __restrict__ A, const f16* __restrict__ Bt,
               int lda, int ldb, int kLen, void* __restrict__ outp, int ldc,
               const float* __restrict__ nrm, float* __restrict__ rowsum) {
    __shared__ __align__(16) f16 As[128 * 32];
    __shared__ __align__(16) f16 Bs[128 * 32];
    // XCD swizzle: 1024 blocks; consecutive same-A-strip blocks -> same XCD (lin&7).
    const int lin = blockIdx.x;
    const int xcd = lin & 7, i = lin >> 3;
    int bx, by, bz;
    if (EPI == 1) { bx = i & 31; by = xcd + 8 * (i >> 5); bz = 0; }
    else         { bx = i & 7;  int s = xcd + 8 * (i >> 3); by = s & 31; bz = s >> 5; }

    const int tid = threadIdx.x;
    const int w = tid >> 6, lane = tid & 63;
    const int row0 = by * 128, col0 = bx * 128;
    const int k_start = bz * kLen;

    const int srow = w * 32 + (lane >> 2);
    const int scol = (lane & 3) * 8;
    const f16* gA = A + (size_t)(row0 + srow) * lda + k_start + scol;
    const f16* gB = Bt + (size_t)(col0 + srow) * ldb + k_start + scol;
    f16* lA0 = As + (w * 32) * 32;
    f16* lA1 = As + (w * 32 + 16) * 32;
    f16* lB0 = Bs + (w * 32) * 32;
    f16* lB1 = Bs + (w * 32 + 16) * 32;

    const int wm = w >> 1, wn = w & 1;
    const int mfm = lane & 15, quad = lane >> 4;
    f32x4 acc[4][4] = {};

    for (int k0 = 0; k0 < kLen; k0 += 32) {
        gload16(gA, lA0);
        gload16(gA + (size_t)16 * lda, lA1);
        gload16(gB, lB0);
        gload16(gB + (size_t)16 * ldb, lB1);
        gA += 32; gB += 32;
        __syncthreads();
        f16x8 af[4], bf[4];
        #pragma unroll
        for (int mi = 0; mi < 4; ++mi)
            af[mi] = *(const f16x8*)&As[(wm * 64 + mi * 16 + mfm) * 32 + quad * 8];
        #pragma unroll
        for (int ni = 0; ni < 4; ++ni)
            bf[ni] = *(const f16x8*)&Bs[(wn * 64 + ni * 16 + mfm) * 32 + quad * 8];
        #pragma unroll
        for (int mi = 0; mi < 4; ++mi)
            #pragma unroll
            for (int ni = 0; ni < 4; ++ni)
                acc[mi][ni] = __builtin_amdgcn_mfma_f32_16x16x32_f16(
                    af[mi], bf[ni], acc[mi][ni], 0, 0, 0);
        __syncthreads();
    }

    const int orow = row0 + wm * 64;
    const int ocol = col0 + wn * 64;
    if (EPI == 1) {
        f16* Eo = (f16*)outp;
        float rs[16] = {};
        #pragma unroll
        for (int ni = 0; ni < 4; ++ni) {
            int col = ocol + ni * 16 + mfm;
            float cs = 10.0f / nrm[col];
            #pragma unroll
            for (int mi = 0; mi < 4; ++mi) {
                #pragma unroll
                for (int r = 0; r < 4; ++r) {
                    int row = orow + mi * 16 + quad * 4 + r;
                    float e = __expf(acc[mi][ni][r] * cs - 10.0f * nrm[row]);
                    Eo[(size_t)row * ldc + col] = (f16)e;
                    rs[mi * 4 + r] += e;
                }
            }
        }
        // reduce each row-sum across the 16 lanes sharing `quad`, one atomic per row
        #pragma unroll
        for (int j = 0; j < 16; ++j) {
            float v = rs[j];
            v += __shfl_xor(v, 1); v += __shfl_xor(v, 2);
            v += __shfl_xor(v, 4); v += __shfl_xor(v, 8);
            if (mfm == 0)
                atomicAdd(&rowsum[orow + (j >> 2) * 16 + quad * 4 + (j & 3)], v);
        }
    } else {
        f16* Oo = (f16*)outp + (size_t)bz * ((size_t)L_ * E2);
        #pragma unroll
        for (int mi = 0; mi < 4; ++mi) {
            #pragma unroll
            for (int r = 0; r < 4; ++r) {
                int row = orow + mi * 16 + quad * 4 + r;
                #pragma unroll
                for (int ni = 0; ni < 4; ++ni)
                    Oo[(size_t)row * ldc + ocol + ni * 16 + mfm] = (f16)acc[mi][ni][r];
            }
        }
    }
}

// ---------------- conv_transpose overlap-add gather: sum split-K partials,
// divide by softmax rowsum, /4 ----------------
__global__ __launch_bounds__(256) void gather_kernel(const f16* __restrict__ OPp,
                                                     const float* __restrict__ rowsum,
                                                     float* __restrict__ out_b) {
    int idx = blockIdx.x * 256 + threadIdx.x;
    if (idx >= C_ * H_ * W_) return;
    int X = idx & 127, Y = (idx >> 7) & 127, c = idx >> 14;
    int kyp = (Y + 1) & 1;
    int kxp = (X + 1) & 1;
    float sum = 0.f;
    #pragma unroll
    for (int ky = kyp; ky < 4; ky += 2) {
        int py = (Y + 1 - ky) >> 1;
        if ((unsigned)py >= 64u) continue;
        #pragma unroll
        for (int kx = kxp; kx < 4; kx += 2) {
            int px = (X + 1 - kx) >> 1;
            if ((unsigned)px >= 64u) continue;
            int p = py * 64 + px;
            size_t off = (size_t)p * E2 + c * 16 + ky * 4 + kx;
            float v = 0.f;
            #pragma unroll
            for (int s = 0; s < KSPLIT; ++s)
                v += (float)OPp[(size_t)s * (L_ * E2) + off];
            sum += v * __builtin_amdgcn_rcpf(rowsum[p]);
        }
    }
    out_b[idx] = 0.25f * sum;
}

extern "C" void kernel_launch(void* const* d_in, const int* in_sizes, int n_in,
                              void* d_out, int out_size, void* d_ws, size_t ws_size,
                              hipStream_t stream) {
    const float* bg = (const float*)d_in[0];
    const float* fg = (const float*)d_in[1];
    float* out = (float*)d_out;
    char* w8 = (char*)d_ws;

    // workspace layout (bytes), total ~98.6 MB (proven >= 114 MB available)
    float* fgs    = (float*)(w8);                 //  4,194,304
    f16*   P_all  = (f16*)  (w8 + 4194304);       // 18,874,368
    float* nrm    = (float*)(w8 + 23068672);      //     65,536
    float* rowsum = (float*)(w8 + 23134208);      //     16,384
    f16*   VT     = (f16*)  (w8 + 23150592);      //  8,388,608 (per-sample, reused)
    f16*   Eb     = (f16*)  (w8 + 31539200);      // 33,554,432 (per-sample, reused)
    f16*   OPp    = (f16*)  (w8 + 65093632);      // 33,554,432 (4 split-K f16 slices)

    resize_kernel<<<(B_ * C_ * HS * WS) / 256, 256, 0, stream>>>(fg, fgs);
    patch_kernel<<<dim3((L_ * K1) / 256, B_), 256, 0, stream>>>(fgs, P_all);
    norm_kernel<<<dim3(L_, B_), 64, 0, stream>>>(P_all, nrm);

    for (int b = 0; b < B_; ++b) {
        const f16* P_b  = P_all + (size_t)b * L_ * K1;
        const float* nrm_b = nrm + (size_t)b * L_;
        const float* bg_b = bg + (size_t)b * C_ * H_ * W_;
        float* out_b = out + (size_t)b * C_ * H_ * W_;

        v_kernel<<<(L_ * E2) / 256, 256, 0, stream>>>(bg_b, VT);
        hipMemsetAsync(rowsum, 0, L_ * sizeof(float), stream);

        // E[p,l] = exp(10*<P_p,P_l>/nrm[l] - 10*nrm[p]); rowsum[p] += E (denominator)
        mfma_gemm<1><<<1024, 256, 0, stream>>>(
            P_b, P_b, K1, K1, K1, Eb, L_, nrm_b, rowsum);

        // OP_z[p,e] = sum_{l in slice z} E[p,l] * VT[e,l]  (f16 partials, no atomics)
        mfma_gemm<0><<<1024, 256, 0, stream>>>(
            Eb, VT, L_, L_, L_ / KSPLIT, OPp, E2, nullptr, nullptr);

        gather_kernel<<<(C_ * H_ * W_) / 256, 256, 0, stream>>>(OPp, rowsum, out_b);
    }
}

// Round 4
// 581.882 us; speedup vs baseline: 5.2744x; 1.2741x over previous
//
#include <hip/hip_runtime.h>
#include <hip/hip_bf16.h>
#include <math.h>

#define B_  4
#define C_  64
#define H_  128
#define W_  128
#define HS  64
#define WS  64
#define L_  4096
#define K1  576
#define E2  1024
#define KSPLIT 4

typedef _Float16 f16;
typedef f16 f16x8 __attribute__((ext_vector_type(8)));
typedef float f32x4 __attribute__((ext_vector_type(4)));

__device__ __forceinline__ void gload16(const void* g, void* l) {
    __builtin_amdgcn_global_load_lds(
        (const __attribute__((address_space(1))) unsigned int*)g,
        (__attribute__((address_space(3))) unsigned int*)l, 16, 0, 0);
}

// ---------------- bilinear resize 128->64, align_corners ----------------
__global__ __launch_bounds__(256) void resize_kernel(const float* __restrict__ fg,
                                                     float* __restrict__ fgs) {
    int idx = blockIdx.x * 256 + threadIdx.x;
    if (idx >= B_ * C_ * HS * WS) return;
    int j = idx & 63, i = (idx >> 6) & 63, bc = idx >> 12;
    const float sc = 127.0f / 63.0f;
    float yf = i * sc, xf = j * sc;
    int y0 = (int)floorf(yf); if (y0 > 127) y0 = 127;
    int x0 = (int)floorf(xf); if (x0 > 127) x0 = 127;
    int y1 = min(y0 + 1, 127), x1 = min(x0 + 1, 127);
    float wy = yf - (float)y0, wx = xf - (float)x0;
    const float* p = fg + (size_t)bc * (H_ * W_);
    float a = p[y0 * W_ + x0], b = p[y0 * W_ + x1];
    float c = p[y1 * W_ + x0], d = p[y1 * W_ + x1];
    float t0 = a * (1.f - wy) + c * wy;
    float t1 = b * (1.f - wy) + d * wy;
    fgs[idx] = t0 * (1.f - wx) + t1 * wx;
}

// ---------------- P[l,k] f16 patches (3x3xC, zero pad 1), batched ----------------
__global__ __launch_bounds__(256) void patch_kernel(const float* __restrict__ fgs,
                                                    f16* __restrict__ P_all) {
    int idx = blockIdx.x * 256 + threadIdx.x;
    int b = blockIdx.y;
    int k = idx % K1, l = idx / K1;
    int c = k / 9, r = k % 9;
    int dy = r / 3, dx = r % 3;
    int ly = l >> 6, lx = l & 63;
    int y = ly - 1 + dy, x = lx - 1 + dx;
    float v = 0.f;
    if ((unsigned)y < 64u && (unsigned)x < 64u)
        v = fgs[((size_t)b * C_ + c) * (HS * WS) + y * WS + x];
    P_all[(size_t)b * L_ * K1 + idx] = (f16)v;
}

// ---------------- norms of f16 patch rows (fp32 accumulate), batched ----------------
__global__ __launch_bounds__(64) void norm_kernel(const f16* __restrict__ P_all,
                                                  float* __restrict__ nrm_all) {
    int l = blockIdx.x, b = blockIdx.y, t = threadIdx.x;
    const f16* row = P_all + ((size_t)b * L_ + l) * K1;
    float s = 0.f;
    for (int k = t; k < K1; k += 64) { float v = (float)row[k]; s = fmaf(v, v, s); }
    #pragma unroll
    for (int off = 32; off; off >>= 1) s += __shfl_down(s, off);
    if (t == 0) nrm_all[b * L_ + l] = fmaxf(sqrtf(s), 1e-4f);
}

// ---------------- VT[e,l] f16 : transposed 4x4xC background patches, per sample ----------------
__global__ __launch_bounds__(256) void v_kernel(const float* __restrict__ bg_b,
                                                f16* __restrict__ VT) {
    int idx = blockIdx.x * 256 + threadIdx.x;
    int l = idx & 4095, e = idx >> 12;
    int c = e >> 4, r = e & 15;
    int ky = r >> 2, kx = r & 3;
    int ly = l >> 6, lx = l & 63;
    int by = 2 * ly - 1 + ky, bx = 2 * lx - 1 + kx;
    float v = 0.f;
    if ((unsigned)by < 128u && (unsigned)bx < 128u)
        v = bg_b[(size_t)c * (H_ * W_) + by * W_ + bx];
    VT[idx] = (f16)v;
}

// ---------------- MFMA gemm_bt: D[M,N] = A[M,K] * Bt[N,K]^T ----------------
// 128x128 tile, 4 waves (2x2 of 64x64), 16x16x32 f16 MFMA, BK=64 via two
// BK-32 panels (32 MFMA per barrier pair; panel layout identical to the
// verified m97 staging so global_load_lds lane order is preserved).
// EPI=1 (score, M=N=4096): E[p,l] = exp(acc*10/nrm[l] - 10*nrm[p]) stored f16;
//       per-row wave-reduced E-sums atomicAdd'ed into rowsum[].
// EPI=0 (PV, M=E2, N=L_, split-K=4): OPT_z[e,p] f16 partials (no atomics).
template <int EPI>
__global__ __launch_bounds__(256)
void mfma_gemm(const f16* __restrict__ A, const f16* __restrict__ Bt,
               int lda, int ldb, int kLen, void* __restrict__ outp, int ldc,
               const float* __restrict__ nrm, float* __restrict__ rowsum) {
    __shared__ __align__(16) f16 As0[128 * 32];
    __shared__ __align__(16) f16 As1[128 * 32];
    __shared__ __align__(16) f16 Bs0[128 * 32];
    __shared__ __align__(16) f16 Bs1[128 * 32];
    // XCD swizzle: blocks sharing an A-strip land on one XCD.
    const int lin = blockIdx.x;
    int bx, by, bz;
    if (EPI == 1) { int xcd = lin & 7, i = lin >> 3; bx = i & 31; by = xcd + 8 * (i >> 5); bz = 0; }
    else          { by = lin & 7; int i = lin >> 3; bx = i & 31; bz = i >> 5; }

    const int tid = threadIdx.x;
    const int w = tid >> 6, lane = tid & 63;
    const int row0 = by * 128, col0 = bx * 128;
    const int k_start = bz * kLen;

    // staging (per panel): wave w covers rows [w*32, w*32+32) in two 16-row issues
    const int srow = w * 32 + (lane >> 2);
    const int scol = (lane & 3) * 8;
    const f16* gA = A + (size_t)(row0 + srow) * lda + k_start + scol;
    const f16* gB = Bt + (size_t)(col0 + srow) * ldb + k_start + scol;
    const int l0 = (w * 32) * 32, l1 = (w * 32 + 16) * 32;

    const int wm = w >> 1, wn = w & 1;
    const int mfm = lane & 15, quad = lane >> 4;
    f32x4 acc[4][4] = {};

    for (int k0 = 0; k0 < kLen; k0 += 64) {
        gload16(gA,                    As0 + l0);
        gload16(gA + (size_t)16 * lda, As0 + l1);
        gload16(gA + 32,               As1 + l0);
        gload16(gA + 32 + (size_t)16 * lda, As1 + l1);
        gload16(gB,                    Bs0 + l0);
        gload16(gB + (size_t)16 * ldb, Bs0 + l1);
        gload16(gB + 32,               Bs1 + l0);
        gload16(gB + 32 + (size_t)16 * ldb, Bs1 + l1);
        gA += 64; gB += 64;
        __syncthreads();
        {
            f16x8 af[4], bf[4];
            #pragma unroll
            for (int mi = 0; mi < 4; ++mi)
                af[mi] = *(const f16x8*)&As0[(wm * 64 + mi * 16 + mfm) * 32 + quad * 8];
            #pragma unroll
            for (int ni = 0; ni < 4; ++ni)
                bf[ni] = *(const f16x8*)&Bs0[(wn * 64 + ni * 16 + mfm) * 32 + quad * 8];
            #pragma unroll
            for (int mi = 0; mi < 4; ++mi)
                #pragma unroll
                for (int ni = 0; ni < 4; ++ni)
                    acc[mi][ni] = __builtin_amdgcn_mfma_f32_16x16x32_f16(
                        af[mi], bf[ni], acc[mi][ni], 0, 0, 0);
        }
        {
            f16x8 af[4], bf[4];
            #pragma unroll
            for (int mi = 0; mi < 4; ++mi)
                af[mi] = *(const f16x8*)&As1[(wm * 64 + mi * 16 + mfm) * 32 + quad * 8];
            #pragma unroll
            for (int ni = 0; ni < 4; ++ni)
                bf[ni] = *(const f16x8*)&Bs1[(wn * 64 + ni * 16 + mfm) * 32 + quad * 8];
            #pragma unroll
            for (int mi = 0; mi < 4; ++mi)
                #pragma unroll
                for (int ni = 0; ni < 4; ++ni)
                    acc[mi][ni] = __builtin_amdgcn_mfma_f32_16x16x32_f16(
                        af[mi], bf[ni], acc[mi][ni], 0, 0, 0);
        }
        __syncthreads();
    }

    const int orow = row0 + wm * 64;
    const int ocol = col0 + wn * 64;
    if (EPI == 1) {
        f16* Eo = (f16*)outp;
        float rowm[16], cs[4];
        #pragma unroll
        for (int j = 0; j < 16; ++j)
            rowm[j] = 10.0f * nrm[orow + (j >> 2) * 16 + quad * 4 + (j & 3)];
        #pragma unroll
        for (int ni = 0; ni < 4; ++ni) cs[ni] = 10.0f / nrm[ocol + ni * 16 + mfm];
        float rs[16] = {};
        #pragma unroll
        for (int ni = 0; ni < 4; ++ni) {
            int col = ocol + ni * 16 + mfm;
            #pragma unroll
            for (int mi = 0; mi < 4; ++mi) {
                #pragma unroll
                for (int r = 0; r < 4; ++r) {
                    int row = orow + mi * 16 + quad * 4 + r;
                    float e = __expf(acc[mi][ni][r] * cs[ni] - rowm[mi * 4 + r]);
                    Eo[(size_t)row * ldc + col] = (f16)e;
                    rs[mi * 4 + r] += e;
                }
            }
        }
        #pragma unroll
        for (int j = 0; j < 16; ++j) {
            float v = rs[j];
            v += __shfl_xor(v, 1); v += __shfl_xor(v, 2);
            v += __shfl_xor(v, 4); v += __shfl_xor(v, 8);
            if (mfm == 0)
                atomicAdd(&rowsum[orow + (j >> 2) * 16 + quad * 4 + (j & 3)], v);
        }
    } else {
        f16* Oo = (f16*)outp + (size_t)bz * ((size_t)E2 * L_);
        #pragma unroll
        for (int mi = 0; mi < 4; ++mi) {
            #pragma unroll
            for (int r = 0; r < 4; ++r) {
                int row = orow + mi * 16 + quad * 4 + r;
                #pragma unroll
                for (int ni = 0; ni < 4; ++ni)
                    Oo[(size_t)row * ldc + ocol + ni * 16 + mfm] = (f16)acc[mi][ni][r];
            }
        }
    }
}

// ---------------- conv_transpose overlap-add gather on OPT[s][e][p] layout:
// sum split-K partials, divide by softmax rowsum, /4. Reads coalesced in p. ----------------
__global__ __launch_bounds__(256) void gather_kernel(const f16* __restrict__ OPT,
                                                     const float* __restrict__ rowsum,
                                                     float* __restrict__ out_b) {
    int idx = blockIdx.x * 256 + threadIdx.x;
    if (idx >= C_ * H_ * W_) return;
    int X = idx & 127, Y = (idx >> 7) & 127, c = idx >> 14;
    int kyp = (Y + 1) & 1;
    int kxp = (X + 1) & 1;
    float sum = 0.f;
    #pragma unroll
    for (int ky = kyp; ky < 4; ky += 2) {
        int py = (Y + 1 - ky) >> 1;
        if ((unsigned)py >= 64u) continue;
        #pragma unroll
        for (int kx = kxp; kx < 4; kx += 2) {
            int px = (X + 1 - kx) >> 1;
            if ((unsigned)px >= 64u) continue;
            int p = py * 64 + px;
            int e = c * 16 + ky * 4 + kx;
            float v = 0.f;
            #pragma unroll
            for (int s = 0; s < KSPLIT; ++s)
                v += (float)OPT[((size_t)s * E2 + e) * L_ + p];
            sum += v * __builtin_amdgcn_rcpf(rowsum[p]);
        }
    }
    out_b[idx] = 0.25f * sum;
}

extern "C" void kernel_launch(void* const* d_in, const int* in_sizes, int n_in,
                              void* d_out, int out_size, void* d_ws, size_t ws_size,
                              hipStream_t stream) {
    const float* bg = (const float*)d_in[0];
    const float* fg = (const float*)d_in[1];
    float* out = (float*)d_out;
    char* w8 = (char*)d_ws;

    // workspace layout (bytes), total ~98.7 MB (proven >= 114 MB available)
    float* fgs        = (float*)(w8);                 //  4,194,304
    f16*   P_all      = (f16*)  (w8 + 4194304);       // 18,874,368
    float* nrm        = (float*)(w8 + 23068672);      //     65,536
    float* rowsum_all = (float*)(w8 + 23134208);      //     65,536 (B_ x L_)
    f16*   VT         = (f16*)  (w8 + 23199744);      //  8,388,608 (per-sample, reused)
    f16*   Eb         = (f16*)  (w8 + 31588352);      // 33,554,432 (per-sample, reused)
    f16*   OPT        = (f16*)  (w8 + 65142784);      // 33,554,432 (4 split-K f16 slices, [s][e][p])

    resize_kernel<<<(B_ * C_ * HS * WS) / 256, 256, 0, stream>>>(fg, fgs);
    patch_kernel<<<dim3((L_ * K1) / 256, B_), 256, 0, stream>>>(fgs, P_all);
    norm_kernel<<<dim3(L_, B_), 64, 0, stream>>>(P_all, nrm);
    hipMemsetAsync(rowsum_all, 0, (size_t)B_ * L_ * sizeof(float), stream);

    for (int b = 0; b < B_; ++b) {
        const f16* P_b     = P_all + (size_t)b * L_ * K1;
        const float* nrm_b = nrm + (size_t)b * L_;
        float* rowsum_b    = rowsum_all + (size_t)b * L_;
        const float* bg_b  = bg + (size_t)b * C_ * H_ * W_;
        float* out_b       = out + (size_t)b * C_ * H_ * W_;

        v_kernel<<<(L_ * E2) / 256, 256, 0, stream>>>(bg_b, VT);

        // E[p,l] = exp(10*<P_p,P_l>/nrm[l] - 10*nrm[p]); rowsum[p] += E
        mfma_gemm<1><<<1024, 256, 0, stream>>>(
            P_b, P_b, K1, K1, K1, Eb, L_, nrm_b, rowsum_b);

        // OPT_z[e,p] = sum_{l in slice z} VT[e,l] * E[p,l]  (f16 partials)
        mfma_gemm<0><<<1024, 256, 0, stream>>>(
            VT, Eb, L_, L_, L_ / KSPLIT, OPT, L_, nullptr, nullptr);

        gather_kernel<<<(C_ * H_ * W_) / 256, 256, 0, stream>>>(OPT, rowsum_b, out_b);
    }
}

// Round 5
// 364.917 us; speedup vs baseline: 8.4103x; 1.5946x over previous
//
#include <hip/hip_runtime.h>
#include <hip/hip_bf16.h>
#include <math.h>

#define B_  4
#define C_  64
#define H_  128
#define W_  128
#define HS  64
#define WS  64
#define L_  4096
#define K1  576
#define E2  1024
#define KSPLIT 4
// f16 subnormal floor is 2^-24 (logit -16.635); values below 2^-25 (-17.33) cast
// to exactly 0. Flag threshold -17.5 is conservative: no nonzero f16 is missed.
#define ZLOG (-17.5f)

typedef _Float16 f16;
typedef f16 f16x8 __attribute__((ext_vector_type(8)));
typedef float f32x4 __attribute__((ext_vector_type(4)));

__device__ __forceinline__ void gload16(const void* g, void* l) {
    __builtin_amdgcn_global_load_lds(
        (const __attribute__((address_space(1))) unsigned int*)g,
        (__attribute__((address_space(3))) unsigned int*)l, 16, 0, 0);
}

// ---------------- bilinear resize 128->64, align_corners ----------------
__global__ __launch_bounds__(256) void resize_kernel(const float* __restrict__ fg,
                                                     float* __restrict__ fgs) {
    int idx = blockIdx.x * 256 + threadIdx.x;
    if (idx >= B_ * C_ * HS * WS) return;
    int j = idx & 63, i = (idx >> 6) & 63, bc = idx >> 12;
    const float sc = 127.0f / 63.0f;
    float yf = i * sc, xf = j * sc;
    int y0 = (int)floorf(yf); if (y0 > 127) y0 = 127;
    int x0 = (int)floorf(xf); if (x0 > 127) x0 = 127;
    int y1 = min(y0 + 1, 127), x1 = min(x0 + 1, 127);
    float wy = yf - (float)y0, wx = xf - (float)x0;
    const float* p = fg + (size_t)bc * (H_ * W_);
    float a = p[y0 * W_ + x0], b = p[y0 * W_ + x1];
    float c = p[y1 * W_ + x0], d = p[y1 * W_ + x1];
    float t0 = a * (1.f - wy) + c * wy;
    float t1 = b * (1.f - wy) + d * wy;
    fgs[idx] = t0 * (1.f - wx) + t1 * wx;
}

// ---------------- P[l,k] f16 patches (3x3xC, zero pad 1), batched ----------------
__global__ __launch_bounds__(256) void patch_kernel(const float* __restrict__ fgs,
                                                    f16* __restrict__ P_all) {
    int idx = blockIdx.x * 256 + threadIdx.x;
    int b = blockIdx.y;
    int k = idx % K1, l = idx / K1;
    int c = k / 9, r = k % 9;
    int dy = r / 3, dx = r % 3;
    int ly = l >> 6, lx = l & 63;
    int y = ly - 1 + dy, x = lx - 1 + dx;
    float v = 0.f;
    if ((unsigned)y < 64u && (unsigned)x < 64u)
        v = fgs[((size_t)b * C_ + c) * (HS * WS) + y * WS + x];
    P_all[(size_t)b * L_ * K1 + idx] = (f16)v;
}

// ---------------- norms of f16 patch rows (fp32 accumulate), batched ----------------
__global__ __launch_bounds__(64) void norm_kernel(const f16* __restrict__ P_all,
                                                  float* __restrict__ nrm_all) {
    int l = blockIdx.x, b = blockIdx.y, t = threadIdx.x;
    const f16* row = P_all + ((size_t)b * L_ + l) * K1;
    float s = 0.f;
    for (int k = t; k < K1; k += 64) { float v = (float)row[k]; s = fmaf(v, v, s); }
    #pragma unroll
    for (int off = 32; off; off >>= 1) s += __shfl_down(s, off);
    if (t == 0) nrm_all[b * L_ + l] = fmaxf(sqrtf(s), 1e-4f);
}

// ---------------- VT[e,l] f16 : transposed 4x4xC background patches, per sample ----------------
__global__ __launch_bounds__(256) void v_kernel(const float* __restrict__ bg_b,
                                                f16* __restrict__ VT) {
    int idx = blockIdx.x * 256 + threadIdx.x;
    int l = idx & 4095, e = idx >> 12;
    int c = e >> 4, r = e & 15;
    int ky = r >> 2, kx = r & 3;
    int ly = l >> 6, lx = l & 63;
    int by = 2 * ly - 1 + ky, bx = 2 * lx - 1 + kx;
    float v = 0.f;
    if ((unsigned)by < 128u && (unsigned)bx < 128u)
        v = bg_b[(size_t)c * (H_ * W_) + by * W_ + bx];
    VT[idx] = (f16)v;
}

// ---------------- MFMA gemm_bt: D[M,N] = A[M,K] * Bt[N,K]^T ----------------
// 128x128 tile, 4 waves (2x2 of 64x64), 16x16x32 f16 MFMA, BK=64 (two BK-32
// panels, 32 MFMA per barrier pair, verified m97 staging).
// EPI=1 (score): E[p,l] = exp(acc*10/nrm[l] - 10*nrm[p]) stored f16, but ONLY
//   for tiles whose max logit > ZLOG (others are all-zero in f16); per-tile
//   nonzero flag written to flags[p_blk*32+l_blk]; rowsum atomics likewise
//   skipped for zero tiles (exact: dropped terms < e^-17.5 each).
// EPI=0 (PV, split-K): skips whole BK-64 chunks whose E-tile flag is 0
//   (block-uniform branch; E memory for those tiles is never read).
template <int EPI>
__global__ __launch_bounds__(256)
void mfma_gemm(const f16* __restrict__ A, const f16* __restrict__ Bt,
               int lda, int ldb, int kLen, void* __restrict__ outp, int ldc,
               const float* __restrict__ nrm, float* __restrict__ rowsum,
               int* __restrict__ flags) {
    __shared__ __align__(16) f16 As0[128 * 32];
    __shared__ __align__(16) f16 As1[128 * 32];
    __shared__ __align__(16) f16 Bs0[128 * 32];
    __shared__ __align__(16) f16 Bs1[128 * 32];
    __shared__ float sred[4];
    const int lin = blockIdx.x;
    int bx, by, bz;
    if (EPI == 1) { int xcd = lin & 7, i = lin >> 3; bx = i & 31; by = xcd + 8 * (i >> 5); bz = 0; }
    else          { by = lin & 7; int i = lin >> 3; bx = i & 31; bz = i >> 5; }

    const int tid = threadIdx.x;
    const int w = tid >> 6, lane = tid & 63;
    const int row0 = by * 128, col0 = bx * 128;
    const int k_start = bz * kLen;

    const int srow = w * 32 + (lane >> 2);
    const int scol = (lane & 3) * 8;
    const f16* gA = A + (size_t)(row0 + srow) * lda + k_start + scol;
    const f16* gB = Bt + (size_t)(col0 + srow) * ldb + k_start + scol;
    const int l0 = (w * 32) * 32, l1 = (w * 32 + 16) * 32;

    const int wm = w >> 1, wn = w & 1;
    const int mfm = lane & 15, quad = lane >> 4;
    f32x4 acc[4][4] = {};

    for (int k0 = 0; k0 < kLen; k0 += 64) {
        if (EPI == 0) {
            // skip chunk if its 128x128 E-tile is all-zero (exact)
            if (!flags[(col0 >> 7) * 32 + ((k_start + k0) >> 7)]) continue;
        }
        gload16(gA + k0,                    As0 + l0);
        gload16(gA + k0 + (size_t)16 * lda, As0 + l1);
        gload16(gA + k0 + 32,               As1 + l0);
        gload16(gA + k0 + 32 + (size_t)16 * lda, As1 + l1);
        gload16(gB + k0,                    Bs0 + l0);
        gload16(gB + k0 + (size_t)16 * ldb, Bs0 + l1);
        gload16(gB + k0 + 32,               Bs1 + l0);
        gload16(gB + k0 + 32 + (size_t)16 * ldb, Bs1 + l1);
        __syncthreads();
        {
            f16x8 af[4], bf[4];
            #pragma unroll
            for (int mi = 0; mi < 4; ++mi)
                af[mi] = *(const f16x8*)&As0[(wm * 64 + mi * 16 + mfm) * 32 + quad * 8];
            #pragma unroll
            for (int ni = 0; ni < 4; ++ni)
                bf[ni] = *(const f16x8*)&Bs0[(wn * 64 + ni * 16 + mfm) * 32 + quad * 8];
            #pragma unroll
            for (int mi = 0; mi < 4; ++mi)
                #pragma unroll
                for (int ni = 0; ni < 4; ++ni)
                    acc[mi][ni] = __builtin_amdgcn_mfma_f32_16x16x32_f16(
                        af[mi], bf[ni], acc[mi][ni], 0, 0, 0);
        }
        {
            f16x8 af[4], bf[4];
            #pragma unroll
            for (int mi = 0; mi < 4; ++mi)
                af[mi] = *(const f16x8*)&As1[(wm * 64 + mi * 16 + mfm) * 32 + quad * 8];
            #pragma unroll
            for (int ni = 0; ni < 4; ++ni)
                bf[ni] = *(const f16x8*)&Bs1[(wn * 64 + ni * 16 + mfm) * 32 + quad * 8];
            #pragma unroll
            for (int mi = 0; mi < 4; ++mi)
                #pragma unroll
                for (int ni = 0; ni < 4; ++ni)
                    acc[mi][ni] = __builtin_amdgcn_mfma_f32_16x16x32_f16(
                        af[mi], bf[ni], acc[mi][ni], 0, 0, 0);
        }
        __syncthreads();
    }

    const int orow = row0 + wm * 64;
    const int ocol = col0 + wn * 64;
    if (EPI == 1) {
        f16* Eo = (f16*)outp;
        float rowm[16], cs[4];
        #pragma unroll
        for (int j = 0; j < 16; ++j)
            rowm[j] = 10.0f * nrm[orow + (j >> 2) * 16 + quad * 4 + (j & 3)];
        #pragma unroll
        for (int ni = 0; ni < 4; ++ni) cs[ni] = 10.0f / nrm[ocol + ni * 16 + mfm];
        // pass 1: rowsums + tile max logit
        float rs[16] = {};
        float mx = -1e30f;
        #pragma unroll
        for (int ni = 0; ni < 4; ++ni)
            #pragma unroll
            for (int mi = 0; mi < 4; ++mi)
                #pragma unroll
                for (int r = 0; r < 4; ++r) {
                    float lg = acc[mi][ni][r] * cs[ni] - rowm[mi * 4 + r];
                    mx = fmaxf(mx, lg);
                    rs[mi * 4 + r] += __expf(lg);
                }
        #pragma unroll
        for (int off = 32; off; off >>= 1) mx = fmaxf(mx, __shfl_xor(mx, off));
        if (lane == 0) sred[w] = mx;
        __syncthreads();
        float bmax = fmaxf(fmaxf(sred[0], sred[1]), fmaxf(sred[2], sred[3]));
        int nz = bmax > ZLOG;
        if (nz) {
            // pass 2: store E tile + rowsum atomics
            #pragma unroll
            for (int ni = 0; ni < 4; ++ni) {
                int col = ocol + ni * 16 + mfm;
                #pragma unroll
                for (int mi = 0; mi < 4; ++mi)
                    #pragma unroll
                    for (int r = 0; r < 4; ++r) {
                        int row = orow + mi * 16 + quad * 4 + r;
                        float e = __expf(acc[mi][ni][r] * cs[ni] - rowm[mi * 4 + r]);
                        Eo[(size_t)row * ldc + col] = (f16)e;
                    }
            }
            #pragma unroll
            for (int j = 0; j < 16; ++j) {
                float v = rs[j];
                v += __shfl_xor(v, 1); v += __shfl_xor(v, 2);
                v += __shfl_xor(v, 4); v += __shfl_xor(v, 8);
                if (mfm == 0)
                    atomicAdd(&rowsum[orow + (j >> 2) * 16 + quad * 4 + (j & 3)], v);
            }
        }
        if (tid == 0) flags[by * 32 + bx] = nz;
    } else {
        f16* Oo = (f16*)outp + (size_t)bz * ((size_t)E2 * L_);
        #pragma unroll
        for (int mi = 0; mi < 4; ++mi) {
            #pragma unroll
            for (int r = 0; r < 4; ++r) {
                int row = orow + mi * 16 + quad * 4 + r;
                #pragma unroll
                for (int ni = 0; ni < 4; ++ni)
                    Oo[(size_t)row * ldc + ocol + ni * 16 + mfm] = (f16)acc[mi][ni][r];
            }
        }
    }
}

// ---------------- conv_transpose overlap-add gather on OPT[s][e][p] layout ----------------
__global__ __launch_bounds__(256) void gather_kernel(const f16* __restrict__ OPT,
                                                     const float* __restrict__ rowsum,
                                                     float* __restrict__ out_b) {
    int idx = blockIdx.x * 256 + threadIdx.x;
    if (idx >= C_ * H_ * W_) return;
    int X = idx & 127, Y = (idx >> 7) & 127, c = idx >> 14;
    int kyp = (Y + 1) & 1;
    int kxp = (X + 1) & 1;
    float sum = 0.f;
    #pragma unroll
    for (int ky = kyp; ky < 4; ky += 2) {
        int py = (Y + 1 - ky) >> 1;
        if ((unsigned)py >= 64u) continue;
        #pragma unroll
        for (int kx = kxp; kx < 4; kx += 2) {
            int px = (X + 1 - kx) >> 1;
            if ((unsigned)px >= 64u) continue;
            int p = py * 64 + px;
            int e = c * 16 + ky * 4 + kx;
            float v = 0.f;
            #pragma unroll
            for (int s = 0; s < KSPLIT; ++s)
                v += (float)OPT[((size_t)s * E2 + e) * L_ + p];
            sum += v * __builtin_amdgcn_rcpf(rowsum[p]);
        }
    }
    out_b[idx] = 0.25f * sum;
}

extern "C" void kernel_launch(void* const* d_in, const int* in_sizes, int n_in,
                              void* d_out, int out_size, void* d_ws, size_t ws_size,
                              hipStream_t stream) {
    const float* bg = (const float*)d_in[0];
    const float* fg = (const float*)d_in[1];
    float* out = (float*)d_out;
    char* w8 = (char*)d_ws;

    // workspace layout (bytes), total ~98.7 MB (proven >= 114 MB available)
    float* fgs        = (float*)(w8);                 //  4,194,304
    f16*   P_all      = (f16*)  (w8 + 4194304);       // 18,874,368
    float* nrm        = (float*)(w8 + 23068672);      //     65,536
    float* rowsum_all = (float*)(w8 + 23134208);      //     65,536 (B_ x L_)
    int*   flags      = (int*)  (w8 + 23199744);      //      4,096 (32x32 tile flags)
    f16*   VT         = (f16*)  (w8 + 23203840);      //  8,388,608 (per-sample, reused)
    f16*   Eb         = (f16*)  (w8 + 31592448);      // 33,554,432 (per-sample, reused)
    f16*   OPT        = (f16*)  (w8 + 65146880);      // 33,554,432 (4 split-K f16 slices, [s][e][p])

    resize_kernel<<<(B_ * C_ * HS * WS) / 256, 256, 0, stream>>>(fg, fgs);
    patch_kernel<<<dim3((L_ * K1) / 256, B_), 256, 0, stream>>>(fgs, P_all);
    norm_kernel<<<dim3(L_, B_), 64, 0, stream>>>(P_all, nrm);
    hipMemsetAsync(rowsum_all, 0, (size_t)B_ * L_ * sizeof(float), stream);

    for (int b = 0; b < B_; ++b) {
        const f16* P_b     = P_all + (size_t)b * L_ * K1;
        const float* nrm_b = nrm + (size_t)b * L_;
        float* rowsum_b    = rowsum_all + (size_t)b * L_;
        const float* bg_b  = bg + (size_t)b * C_ * H_ * W_;
        float* out_b       = out + (size_t)b * C_ * H_ * W_;

        v_kernel<<<(L_ * E2) / 256, 256, 0, stream>>>(bg_b, VT);

        // E[p,l] = exp(10*<P_p,P_l>/nrm[l] - 10*nrm[p]); rowsum[p] += E; tile flags
        mfma_gemm<1><<<1024, 256, 0, stream>>>(
            P_b, P_b, K1, K1, K1, Eb, L_, nrm_b, rowsum_b, flags);

        // OPT_z[e,p] = sum_{l in slice z} VT[e,l] * E[p,l]  (skips zero E-tiles)
        mfma_gemm<0><<<1024, 256, 0, stream>>>(
            VT, Eb, L_, L_, L_ / KSPLIT, OPT, L_, nullptr, nullptr, flags);

        gather_kernel<<<(C_ * H_ * W_) / 256, 256, 0, stream>>>(OPT, rowsum_b, out_b);
    }
}